// Round 6
// baseline (316.800 us; speedup 1.0000x reference)
//
#include <hip/hip_runtime.h>
#include <hip/hip_bf16.h>
#include <math.h>

// Problem constants: B=4, T=2048, K(head dim)=128, H=8
#define T_SEQ 2048
#define NH 8
#define DK 128
#define BATCH 4
#define KT 64     // attention KV tile
#define QTILE 128 // Q rows per block (4 q-waves x 32 rows; x2 key-half waves)
#define NT (T_SEQ / KT)

// Q pre-scale: (1/sqrt(128)) * log2(e)  -> S feeds exp2 directly
#define QSCALE 0.1275174435f

typedef __attribute__((ext_vector_type(8))) short short8;
typedef __attribute__((ext_vector_type(4))) float floatx4;
typedef __attribute__((ext_vector_type(16))) float floatx16;
typedef __attribute__((ext_vector_type(8))) _Float16 half8;

typedef const __attribute__((address_space(1))) unsigned int gu32_t;
typedef __attribute__((address_space(3))) unsigned int lu32_t;

#if defined(__has_builtin)
#if __has_builtin(__builtin_amdgcn_exp2f)
#define EXP2F(x) __builtin_amdgcn_exp2f(x)
#endif
#endif
#ifndef EXP2F
#define EXP2F(x) exp2f(x)
#endif

__device__ __forceinline__ unsigned short f2bf(float f) {
  union { float f; unsigned u; } v; v.f = f;
  unsigned u = v.u;
  return (unsigned short)((u + 0x7fffu + ((u >> 16) & 1u)) >> 16);  // RNE
}

__device__ __forceinline__ unsigned short f2h(float f) {
  union { _Float16 h; unsigned short u; } v; v.h = (_Float16)f;
  return v.u;
}

__device__ __forceinline__ unsigned pk2bf(float a, float b) {
  __hip_bfloat162 h = __float22bfloat162_rn(make_float2(a, b));
  return *(unsigned*)&h;   // low 16 = a, high 16 = b
}

__device__ __forceinline__ unsigned pkh(float a, float b) {
  union { _Float16 h[2]; unsigned u; } v;
  v.h[0] = (_Float16)a; v.h[1] = (_Float16)b;
  return v.u;
}

// ---------------------------------------------------------------------------
// Kernel 0: one-time weight conversion fp32 -> bf16 (unchanged).
// ---------------------------------------------------------------------------
__global__ __launch_bounds__(256) void convert_w_kernel(
    const float* __restrict__ Wq, const float* __restrict__ Wk,
    const float* __restrict__ Wv, const float* __restrict__ Wu,
    unsigned short* __restrict__ Wqb, unsigned short* __restrict__ Wkb,
    unsigned short* __restrict__ Wvb, unsigned short* __restrict__ Wub)
{
  int which = blockIdx.x >> 6;
  const float* src = (which == 0) ? Wq : (which == 1) ? Wk : (which == 2) ? Wv : Wu;
  unsigned short* dst = (which == 0) ? Wqb : (which == 1) ? Wkb : (which == 2) ? Wvb : Wub;
  float s = (which == 0) ? QSCALE : 1.0f;
  size_t off = ((size_t)(blockIdx.x & 63) * 256 + threadIdx.x) * 8;
  float4 a = *(const float4*)(src + off);
  float4 c = *(const float4*)(src + off + 4);
  uint4 o;
  o.x = pk2bf(a.x * s, a.y * s);
  o.y = pk2bf(a.z * s, a.w * s);
  o.z = pk2bf(c.x * s, c.y * s);
  o.w = pk2bf(c.z * s, c.w * s);
  *(uint4*)(dst + off) = o;
}

// ---------------------------------------------------------------------------
// Kernel 1: fused QKV projection (unchanged).
// ---------------------------------------------------------------------------
__global__ __launch_bounds__(256) void qkv_proj_kernel(
    const float* __restrict__ x,
    const unsigned short* __restrict__ Wqb,
    const unsigned short* __restrict__ Wkb,
    const unsigned short* __restrict__ Wvb,
    unsigned short* __restrict__ Qw, unsigned short* __restrict__ Kw,
    unsigned short* __restrict__ Vt)
{
  __shared__ __align__(16) unsigned short Tile[128 * 136];   // 34.8 KB
  int h  = blockIdx.x;             // head = col block (128 cols)
  int nb = h * 128;
  int mb = blockIdx.y * 128;       // row base within 8192
  int w3 = blockIdx.z;             // 0=Q 1=K 2=V
  int b = mb >> 11, t0 = mb & (T_SEQ - 1);
  int t = threadIdx.x, wave = t >> 6, lane = t & 63;
  int n = lane & 15, q = lane >> 4;
  int srow = lane >> 4;            // readback row-subindex
  int scol = (lane & 15) * 8;      // readback col (shorts)

  const unsigned short* Wsrc = (w3 == 0) ? Wqb : ((w3 == 1) ? Wkb : Wvb);
  const unsigned short* Wb = Wsrc + (size_t)nb * DK;
  #pragma unroll
  for (int j = 0; j < 8; ++j) {
    int inst = wave * 8 + j;              // 32 insts cover 128 rows
    int row = inst * 4 + (lane >> 4);     // 4 rows per inst
    int ck = (lane & 15) ^ (row & 15);    // pre-swizzled source chunk
    __builtin_amdgcn_global_load_lds(
        (gu32_t*)(Wb + (size_t)row * DK + ck * 8),
        (lu32_t*)(&Tile[inst * 512]), 16, 0, 0);
  }

  // x A-fragments for this wave's 32 rows (fp32 -> bf16 in regs)
  short8 xa[2][4];
  #pragma unroll
  for (int rg = 0; rg < 2; ++rg) {
    const float* xr = x + (size_t)(mb + wave*32 + rg*16 + n) * DK;
    #pragma unroll
    for (int kc = 0; kc < 4; ++kc) {
      float4 f0 = *(const float4*)(xr + kc*32 + q*8);
      float4 f1 = *(const float4*)(xr + kc*32 + q*8 + 4);
      union { short8 s; unsigned u[4]; } pk;
      pk.u[0] = pk2bf(f0.x, f0.y); pk.u[1] = pk2bf(f0.z, f0.w);
      pk.u[2] = pk2bf(f1.x, f1.y); pk.u[3] = pk2bf(f1.z, f1.w);
      xa[rg][kc] = pk.s;
    }
  }

  __syncthreads();   // W staged

  if (w3 < 2) {
    floatx4 acc[2][8];
    #pragma unroll
    for (int rg = 0; rg < 2; ++rg)
      #pragma unroll
      for (int cg = 0; cg < 8; ++cg)
        acc[rg][cg] = (floatx4){0.f, 0.f, 0.f, 0.f};
    #pragma unroll
    for (int kc = 0; kc < 4; ++kc) {
      int p = ((kc*4 + q) ^ n) * 8;       // swizzled chunk (shorts)
      #pragma unroll
      for (int cg = 0; cg < 8; ++cg) {
        short8 bk = *(const short8*)&Tile[(cg*16 + n)*DK + p];
        acc[0][cg] = __builtin_amdgcn_mfma_f32_16x16x32_bf16(xa[0][kc], bk, acc[0][cg], 0, 0, 0);
        acc[1][cg] = __builtin_amdgcn_mfma_f32_16x16x32_bf16(xa[1][kc], bk, acc[1][cg], 0, 0, 0);
      }
    }
    __syncthreads();   // all W reads done before C overwrites Tile
    #pragma unroll
    for (int rg = 0; rg < 2; ++rg)
      #pragma unroll
      for (int cg = 0; cg < 8; ++cg)
        #pragma unroll
        for (int r = 0; r < 4; ++r)
          Tile[(wave*32 + rg*16 + q*4 + r)*136 + cg*16 + n] = f2bf(acc[rg][cg][r]);
    __syncthreads();
    unsigned short* gb = ((w3 == 0) ? Qw : Kw) +
        (((size_t)(b*NH + h))*T_SEQ + t0)*DK;
    #pragma unroll
    for (int i = 0; i < 8; ++i) {
      int row = wave*32 + i*4 + srow;
      *(uint4*)(gb + (size_t)row*DK + scol) = *(const uint4*)&Tile[row*136 + scol];
    }
  } else {
    // V: transposed C-tile (rows = d, cols = tt) via swapped operands
    floatx4 accv[8][2];
    #pragma unroll
    for (int mt = 0; mt < 8; ++mt)
      #pragma unroll
      for (int nt = 0; nt < 2; ++nt)
        accv[mt][nt] = (floatx4){0.f, 0.f, 0.f, 0.f};
    #pragma unroll
    for (int kc = 0; kc < 4; ++kc) {
      int p = ((kc*4 + q) ^ n) * 8;
      #pragma unroll
      for (int mt = 0; mt < 8; ++mt) {
        short8 wa = *(const short8*)&Tile[(mt*16 + n)*DK + p];
        accv[mt][0] = __builtin_amdgcn_mfma_f32_16x16x32_bf16(wa, xa[0][kc], accv[mt][0], 0, 0, 0);
        accv[mt][1] = __builtin_amdgcn_mfma_f32_16x16x32_bf16(wa, xa[1][kc], accv[mt][1], 0, 0, 0);
      }
    }
    __syncthreads();
    #pragma unroll
    for (int mt = 0; mt < 8; ++mt)
      #pragma unroll
      for (int nt = 0; nt < 2; ++nt)
        #pragma unroll
        for (int r = 0; r < 4; ++r)
          Tile[(mt*16 + q*4 + r)*136 + wave*32 + nt*16 + n] = f2h(accv[mt][nt][r]);
    __syncthreads();
    unsigned short* gb = Vt + ((size_t)(b*NH + h))*DK*T_SEQ + t0;
    #pragma unroll
    for (int i = 0; i < 8; ++i) {
      int d = wave*32 + i*4 + srow;
      *(uint4*)(gb + (size_t)d*T_SEQ + scol) = *(const uint4*)&Tile[d*136 + scol];
    }
  }
}

// ---------------------------------------------------------------------------
// Kernel 2: flash attention v5 — key-half wave split for 4 waves/SIMD.
//  - 512-thr blocks (8 waves): wq = w&3 picks 32 q-rows, kh = w>>2 picks
//    key-half (0-31 / 32-63) of each KT=64 tile. Per-wave loop work halves;
//    partial Oacc/lp per wave; one-time LDS combine (overlays dead K/V bufs).
//  - LDS 66 KB/block -> 2 blocks/CU = 16 waves/CU = 4 waves/SIMD (was 2):
//    doubles latency hiding; the per-wave dep chain was the round-5 binder.
//  - Counted-vmcnt pipeline kept (4 loads/wave/tile -> vmcnt(4)).
//  - QK^T accumulator split even/odd kc for 2-way MFMA ILP.
//  - XCD-cluster remap + setprio kept.
// ---------------------------------------------------------------------------
__global__ __launch_bounds__(512, 4) void attn_kernel(
    const unsigned short* __restrict__ Qw, const unsigned short* __restrict__ Kw,
    const unsigned short* __restrict__ Vt, unsigned short* __restrict__ attn_out)
{
  // [0, 16384): Ks[2][KT*DK/2...] -> Ks buf b at SM + b*8192 (shorts? see below)
  // Layout (shorts): Ks[2][64*128] = 16384, Vs[2][128*64] = 16384, lp 256.
  __shared__ __align__(16) unsigned short SM[2*KT*DK + 2*DK*KT + 256];
  unsigned short* KsBase = SM;                    // + buf*KT*DK
  unsigned short* VsBase = SM + 2*KT*DK;          // + buf*DK*KT
  float* combS = (float*)SM;                      // overlay after main loop
  float* lpS   = (float*)(SM + 2*KT*DK + 2*DK*KT);

  int bid = blockIdx.x;
  int g5 = bid & 31, qt = bid >> 5;       // XCD-clustered: (b,h) fixed mod 32
  int h = g5 & 7, b = g5 >> 3;
  size_t base = ((size_t)(b * NH + h)) * T_SEQ * DK;
  const unsigned short* Qb = Qw + base;
  const unsigned short* Kb = Kw + base;
  const unsigned short* Vb = Vt + base;   // [128][2048] fp16
  int t = threadIdx.x, w = t >> 6, lane = t & 63;
  int wq = w & 3, kh = w >> 2;
  int l31 = lane & 31, l15 = lane & 15, hi = lane >> 5;
  bool hb = (hi != 0);

  short8 qf[8];
  {
    const unsigned short* qr = Qb + (size_t)(qt*QTILE + wq*32 + l31) * DK;
    #pragma unroll
    for (int kc = 0; kc < 8; ++kc)
      qf[kc] = *(const short8*)(qr + kc*16 + hi*8);
  }
  floatx16 Oacc[4];
  #pragma unroll
  for (int dt = 0; dt < 4; ++dt)
    #pragma unroll
    for (int r = 0; r < 16; ++r) Oacc[dt][r] = 0.f;
  float lp = 0.f;

  int kkey_lo = lane >> 4;
  int kck     = lane & 15;
  int vd_lo   = lane >> 3;
  int vck     = lane & 7;
  int cv      = vck ^ vd_lo;

  // 8 waves, 2 insts each -> 16 insts cover the tile (same totals as v4).
  #define STAGE_K(KTI, BUFI)                                                    \
    {                                                                           \
      _Pragma("unroll")                                                         \
      for (int j = 0; j < 2; ++j) {                                             \
        int inst = w*2 + j;                                                     \
        int key = inst*4 + kkey_lo;                                             \
        int ck = kck ^ (key & 15);                                              \
        __builtin_amdgcn_global_load_lds(                                       \
            (gu32_t*)(Kb + ((size_t)((KTI)*KT + key))*DK + ck*8),               \
            (lu32_t*)(KsBase + (BUFI)*KT*DK + inst*512), 16, 0, 0);             \
      }                                                                         \
    }

  #define STAGE_V(KTI, BUFI)                                                    \
    {                                                                           \
      _Pragma("unroll")                                                         \
      for (int j = 0; j < 2; ++j) {                                             \
        int inst = w*2 + j;                                                     \
        int d = inst*8 + vd_lo;                                                 \
        __builtin_amdgcn_global_load_lds(                                       \
            (gu32_t*)(Vb + (size_t)d*T_SEQ + (KTI)*KT + cv*8),                  \
            (lu32_t*)(VsBase + (BUFI)*DK*KT + inst*512), 16, 0, 0);             \
      }                                                                         \
    }

  // 2-deep prologue: 8 loads/wave outstanding (after 8 Q loads).
  STAGE_K(0, 0); STAGE_V(0, 0);
  STAGE_K(1, 1); STAGE_V(1, 1);

  for (int kt = 0; kt < NT; ++kt) {
    int buf = kt & 1;
    // Wait for tile kt (leave tile kt+1's 4 loads in flight), then sync.
    if (kt + 1 < NT) {
      asm volatile("s_waitcnt vmcnt(4)" ::: "memory");
    } else {
      asm volatile("s_waitcnt vmcnt(0)" ::: "memory");
    }
    __builtin_amdgcn_s_barrier();

    const unsigned short* KsL = KsBase + buf*KT*DK;
    const unsigned short* VsL = VsBase + buf*DK*KT;

    // QK^T for this wave's key-half: keys kh*32 + 0..31.
    floatx16 sa, sb;
    #pragma unroll
    for (int r = 0; r < 16; ++r) { sa[r] = 0.f; sb[r] = 0.f; }
    __builtin_amdgcn_s_setprio(1);
    #pragma unroll
    for (int kc = 0; kc < 8; kc += 2) {
      int cp0 = (2*kc + hi) ^ l15;
      int cp1 = (2*(kc+1) + hi) ^ l15;
      short8 ak0 = *(const short8*)&KsL[(kh*32 + l31)*DK + cp0*8];
      short8 ak1 = *(const short8*)&KsL[(kh*32 + l31)*DK + cp1*8];
      sa = __builtin_amdgcn_mfma_f32_32x32x16_bf16(ak0, qf[kc],   sa, 0, 0, 0);
      sb = __builtin_amdgcn_mfma_f32_32x32x16_bf16(ak1, qf[kc+1], sb, 0, 0, 0);
    }
    __builtin_amdgcn_s_setprio(0);

    float e[16];
    #pragma unroll
    for (int r = 0; r < 16; ++r) e[r] = EXP2F(sa[r] + sb[r]);
    float s = 0.f;
    #pragma unroll
    for (int r = 0; r < 16; ++r) s += e[r];
    lp += s;
    unsigned p[8];
    #pragma unroll
    for (int i = 0; i < 8; ++i) p[i] = pkh(e[2*i], e[2*i + 1]);
    #pragma unroll
    for (int m = 0; m < 2; ++m) {
      unsigned lo0 = p[4*m], lo1 = p[4*m + 1];
      unsigned up0 = p[4*m + 2], up1 = p[4*m + 3];
      unsigned s0 = hb ? lo0 : up0;
      unsigned s1 = hb ? lo1 : up1;
      unsigned r0 = __shfl_xor(s0, 32, 64);
      unsigned r1 = __shfl_xor(s1, 32, 64);
      union { half8 hv; unsigned u[4]; } fm;
      fm.u[0] = hb ? r0 : lo0;
      fm.u[1] = hb ? r1 : lo1;
      fm.u[2] = hb ? up0 : r0;
      fm.u[3] = hb ? up1 : r1;
      int cp = (4*kh + 2*m + hi) ^ (l31 & 7);
      __builtin_amdgcn_s_setprio(1);
      #pragma unroll
      for (int dt = 0; dt < 4; ++dt) {
        int d = dt*32 + l31;
        half8 bv = *(const half8*)&VsL[d*KT + cp*8];
        Oacc[dt] = __builtin_amdgcn_mfma_f32_32x32x16_f16(fm.hv, bv, Oacc[dt], 0, 0, 0);
      }
      __builtin_amdgcn_s_setprio(0);
    }
    // All LDS reads of buf are register-consumed; sync, then refill buf
    // with tile kt+2 (loads fly until the vmcnt(4) two iterations out).
    __builtin_amdgcn_s_barrier();
    if (kt + 2 < NT) {
      STAGE_K(kt + 2, buf);
      STAGE_V(kt + 2, buf);
    }
  }

  // Per-wave partial denominator over its 32 keys (both hi-halves).
  float lpt = lp + __shfl_xor(lp, 32, 64);

  // Combine key-halves: kh=1 publishes partial O (+lp) via LDS overlay
  // (K/V buffers are dead); kh=0 merges, normalizes, stores.
  __syncthreads();
  if (kh == 1) {
    if (hi == 0) lpS[wq*32 + l31] = lpt;
    #pragma unroll
    for (int dt = 0; dt < 4; ++dt)
      #pragma unroll
      for (int r = 0; r < 16; ++r) {
        int row = (r & 3) + 8*(r >> 2) + 4*hi;
        combS[wq*4096 + row*128 + dt*32 + l31] = Oacc[dt][r];
      }
  }
  __syncthreads();
  if (kh == 0) {
    float rinv = 1.0f / (lpt + lpS[wq*32 + l31]);
    float ri[16];
    #pragma unroll
    for (int r = 0; r < 16; ++r) {
      int row = (r & 3) + 8*(r >> 2) + 4*hi;
      ri[r] = __shfl(rinv, row, 64);
    }
    #pragma unroll
    for (int dt = 0; dt < 4; ++dt)
      #pragma unroll
      for (int r = 0; r < 16; ++r) {
        int row = (r & 3) + 8*(r >> 2) + 4*hi;
        int trow = qt*QTILE + wq*32 + row;
        int col  = h*DK + dt*32 + l31;
        float v = Oacc[dt][r] + combS[wq*4096 + row*128 + dt*32 + l31];
        attn_out[((size_t)b*T_SEQ + trow)*1024 + col] = f2bf(v * ri[r]);
      }
  }
}

// ---------------------------------------------------------------------------
// Kernel 3: out = attn(8192,1024)bf16 @ Wu^T + bu (unchanged).
// ---------------------------------------------------------------------------
__global__ __launch_bounds__(256) void out_proj_kernel(
    const unsigned short* __restrict__ attnb, const unsigned short* __restrict__ Wub,
    const float* __restrict__ bu, float* __restrict__ out)
{
  int mb = blockIdx.x * 16;
  int t = threadIdx.x, wave = t >> 6, lane = t & 63;
  int n = lane & 15, q = lane >> 4;
  int nb2 = wave * 32;
  floatx4 acc[2];
  acc[0] = (floatx4){0.f,0.f,0.f,0.f};
  acc[1] = (floatx4){0.f,0.f,0.f,0.f};
  const unsigned short* ap = attnb + (size_t)(mb + n) * 1024;
  #pragma unroll 8
  for (int kc = 0; kc < 32; ++kc) {
    int ko = kc*32 + q*8;
    short8 a0 = *(const short8*)(ap + ko);
    #pragma unroll
    for (int cg = 0; cg < 2; ++cg) {
      short8 bw = *(const short8*)(Wub + (size_t)(nb2 + cg*16 + n) * 1024 + ko);
      acc[cg] = __builtin_amdgcn_mfma_f32_16x16x32_bf16(a0, bw, acc[cg], 0, 0, 0);
    }
  }
  #pragma unroll
  for (int cg = 0; cg < 2; ++cg)
    #pragma unroll
    for (int r = 0; r < 4; ++r) {
      int m = mb + q*4 + r;
      int c = nb2 + cg*16 + n;
      out[(size_t)m * 128 + c] = acc[cg][r] + bu[c];
    }
}

// ---------------------------------------------------------------------------
extern "C" void kernel_launch(void* const* d_in, const int* in_sizes, int n_in,
                              void* d_out, int out_size, void* d_ws, size_t ws_size,
                              hipStream_t stream) {
  const float* x  = (const float*)d_in[0];
  const float* Wq = (const float*)d_in[1];
  const float* Wk = (const float*)d_in[2];
  const float* Wv = (const float*)d_in[3];
  const float* Wu = (const float*)d_in[4];
  const float* bu = (const float*)d_in[5];
  float* out = (float*)d_out;

  const size_t NE  = (size_t)BATCH * NH * T_SEQ * DK;  // 8,388,608 elems
  const size_t WEL = (size_t)DK * DK * NH;             // 131,072 elems per W
  unsigned short* Qw   = (unsigned short*)d_ws;
  unsigned short* Kw   = Qw + NE;
  unsigned short* Vt   = Kw + NE;
  unsigned short* attn = Vt + NE;
  unsigned short* Wqb  = attn + NE;
  unsigned short* Wkb  = Wqb + WEL;
  unsigned short* Wvb  = Wkb + WEL;
  unsigned short* Wub  = Wvb + WEL;
  if (ws_size < (4 * NE + 4 * WEL) * sizeof(unsigned short)) return;

  convert_w_kernel<<<256, 256, 0, stream>>>(Wq, Wk, Wv, Wu, Wqb, Wkb, Wvb, Wub);
  dim3 g1(8, 64, 3);
  qkv_proj_kernel<<<g1, 256, 0, stream>>>(x, Wqb, Wkb, Wvb, Qw, Kw, Vt);
  attn_kernel<<<BATCH * NH * (T_SEQ / QTILE), 512, 0, stream>>>(Qw, Kw, Vt, attn);
  out_proj_kernel<<<BATCH * T_SEQ / 16, 256, 0, stream>>>(attn, Wub, bu, out);
}

// Round 7
// 218.608 us; speedup vs baseline: 1.4492x; 1.4492x over previous
//
#include <hip/hip_runtime.h>
#include <hip/hip_bf16.h>
#include <math.h>

// Problem constants: B=4, T=2048, K(head dim)=128, H=8
#define T_SEQ 2048
#define NH 8
#define DK 128
#define BATCH 4
#define KT 64     // v4 fallback KV tile
#define KT2 32    // split-K KV tile (32 KB LDS -> 3 blocks/CU)
#define QTILE 128 // Q rows per block (4 waves x 32 rows)
#define NT (T_SEQ / KT)
#define NT2 (1024 / KT2)   // tiles per key-half

// Q pre-scale: (1/sqrt(128)) * log2(e)  -> S feeds exp2 directly
#define QSCALE 0.1275174435f

typedef __attribute__((ext_vector_type(8))) short short8;
typedef __attribute__((ext_vector_type(4))) float floatx4;
typedef __attribute__((ext_vector_type(16))) float floatx16;
typedef __attribute__((ext_vector_type(8))) _Float16 half8;

typedef const __attribute__((address_space(1))) unsigned int gu32_t;
typedef __attribute__((address_space(3))) unsigned int lu32_t;

#if defined(__has_builtin)
#if __has_builtin(__builtin_amdgcn_exp2f)
#define EXP2F(x) __builtin_amdgcn_exp2f(x)
#endif
#endif
#ifndef EXP2F
#define EXP2F(x) exp2f(x)
#endif

__device__ __forceinline__ unsigned short f2bf(float f) {
  union { float f; unsigned u; } v; v.f = f;
  unsigned u = v.u;
  return (unsigned short)((u + 0x7fffu + ((u >> 16) & 1u)) >> 16);  // RNE
}

__device__ __forceinline__ unsigned short f2h(float f) {
  union { _Float16 h; unsigned short u; } v; v.h = (_Float16)f;
  return v.u;
}

__device__ __forceinline__ float h2f(unsigned short u) {
  union { unsigned short u; _Float16 h; } v; v.u = u;
  return (float)v.h;
}

__device__ __forceinline__ unsigned pk2bf(float a, float b) {
  __hip_bfloat162 h = __float22bfloat162_rn(make_float2(a, b));
  return *(unsigned*)&h;   // low 16 = a, high 16 = b
}

__device__ __forceinline__ unsigned pkh(float a, float b) {
  union { _Float16 h[2]; unsigned u; } v;
  v.h[0] = (_Float16)a; v.h[1] = (_Float16)b;
  return v.u;
}

// ---------------------------------------------------------------------------
// Kernel 0: one-time weight conversion fp32 -> bf16 (unchanged).
// ---------------------------------------------------------------------------
__global__ __launch_bounds__(256) void convert_w_kernel(
    const float* __restrict__ Wq, const float* __restrict__ Wk,
    const float* __restrict__ Wv, const float* __restrict__ Wu,
    unsigned short* __restrict__ Wqb, unsigned short* __restrict__ Wkb,
    unsigned short* __restrict__ Wvb, unsigned short* __restrict__ Wub)
{
  int which = blockIdx.x >> 6;
  const float* src = (which == 0) ? Wq : (which == 1) ? Wk : (which == 2) ? Wv : Wu;
  unsigned short* dst = (which == 0) ? Wqb : (which == 1) ? Wkb : (which == 2) ? Wvb : Wub;
  float s = (which == 0) ? QSCALE : 1.0f;
  size_t off = ((size_t)(blockIdx.x & 63) * 256 + threadIdx.x) * 8;
  float4 a = *(const float4*)(src + off);
  float4 c = *(const float4*)(src + off + 4);
  uint4 o;
  o.x = pk2bf(a.x * s, a.y * s);
  o.y = pk2bf(a.z * s, a.w * s);
  o.z = pk2bf(c.x * s, c.y * s);
  o.w = pk2bf(c.z * s, c.w * s);
  *(uint4*)(dst + off) = o;
}

// ---------------------------------------------------------------------------
// Kernel 1: fused QKV projection (unchanged).
// ---------------------------------------------------------------------------
__global__ __launch_bounds__(256) void qkv_proj_kernel(
    const float* __restrict__ x,
    const unsigned short* __restrict__ Wqb,
    const unsigned short* __restrict__ Wkb,
    const unsigned short* __restrict__ Wvb,
    unsigned short* __restrict__ Qw, unsigned short* __restrict__ Kw,
    unsigned short* __restrict__ Vt)
{
  __shared__ __align__(16) unsigned short Tile[128 * 136];   // 34.8 KB
  int h  = blockIdx.x;
  int nb = h * 128;
  int mb = blockIdx.y * 128;
  int w3 = blockIdx.z;             // 0=Q 1=K 2=V
  int b = mb >> 11, t0 = mb & (T_SEQ - 1);
  int t = threadIdx.x, wave = t >> 6, lane = t & 63;
  int n = lane & 15, q = lane >> 4;
  int srow = lane >> 4;
  int scol = (lane & 15) * 8;

  const unsigned short* Wsrc = (w3 == 0) ? Wqb : ((w3 == 1) ? Wkb : Wvb);
  const unsigned short* Wb = Wsrc + (size_t)nb * DK;
  #pragma unroll
  for (int j = 0; j < 8; ++j) {
    int inst = wave * 8 + j;
    int row = inst * 4 + (lane >> 4);
    int ck = (lane & 15) ^ (row & 15);
    __builtin_amdgcn_global_load_lds(
        (gu32_t*)(Wb + (size_t)row * DK + ck * 8),
        (lu32_t*)(&Tile[inst * 512]), 16, 0, 0);
  }

  short8 xa[2][4];
  #pragma unroll
  for (int rg = 0; rg < 2; ++rg) {
    const float* xr = x + (size_t)(mb + wave*32 + rg*16 + n) * DK;
    #pragma unroll
    for (int kc = 0; kc < 4; ++kc) {
      float4 f0 = *(const float4*)(xr + kc*32 + q*8);
      float4 f1 = *(const float4*)(xr + kc*32 + q*8 + 4);
      union { short8 s; unsigned u[4]; } pk;
      pk.u[0] = pk2bf(f0.x, f0.y); pk.u[1] = pk2bf(f0.z, f0.w);
      pk.u[2] = pk2bf(f1.x, f1.y); pk.u[3] = pk2bf(f1.z, f1.w);
      xa[rg][kc] = pk.s;
    }
  }

  __syncthreads();   // W staged

  if (w3 < 2) {
    floatx4 acc[2][8];
    #pragma unroll
    for (int rg = 0; rg < 2; ++rg)
      #pragma unroll
      for (int cg = 0; cg < 8; ++cg)
        acc[rg][cg] = (floatx4){0.f, 0.f, 0.f, 0.f};
    #pragma unroll
    for (int kc = 0; kc < 4; ++kc) {
      int p = ((kc*4 + q) ^ n) * 8;
      #pragma unroll
      for (int cg = 0; cg < 8; ++cg) {
        short8 bk = *(const short8*)&Tile[(cg*16 + n)*DK + p];
        acc[0][cg] = __builtin_amdgcn_mfma_f32_16x16x32_bf16(xa[0][kc], bk, acc[0][cg], 0, 0, 0);
        acc[1][cg] = __builtin_amdgcn_mfma_f32_16x16x32_bf16(xa[1][kc], bk, acc[1][cg], 0, 0, 0);
      }
    }
    __syncthreads();
    #pragma unroll
    for (int rg = 0; rg < 2; ++rg)
      #pragma unroll
      for (int cg = 0; cg < 8; ++cg)
        #pragma unroll
        for (int r = 0; r < 4; ++r)
          Tile[(wave*32 + rg*16 + q*4 + r)*136 + cg*16 + n] = f2bf(acc[rg][cg][r]);
    __syncthreads();
    unsigned short* gb = ((w3 == 0) ? Qw : Kw) +
        (((size_t)(b*NH + h))*T_SEQ + t0)*DK;
    #pragma unroll
    for (int i = 0; i < 8; ++i) {
      int row = wave*32 + i*4 + srow;
      *(uint4*)(gb + (size_t)row*DK + scol) = *(const uint4*)&Tile[row*136 + scol];
    }
  } else {
    floatx4 accv[8][2];
    #pragma unroll
    for (int mt = 0; mt < 8; ++mt)
      #pragma unroll
      for (int nt = 0; nt < 2; ++nt)
        accv[mt][nt] = (floatx4){0.f, 0.f, 0.f, 0.f};
    #pragma unroll
    for (int kc = 0; kc < 4; ++kc) {
      int p = ((kc*4 + q) ^ n) * 8;
      #pragma unroll
      for (int mt = 0; mt < 8; ++mt) {
        short8 wa = *(const short8*)&Tile[(mt*16 + n)*DK + p];
        accv[mt][0] = __builtin_amdgcn_mfma_f32_16x16x32_bf16(wa, xa[0][kc], accv[mt][0], 0, 0, 0);
        accv[mt][1] = __builtin_amdgcn_mfma_f32_16x16x32_bf16(wa, xa[1][kc], accv[mt][1], 0, 0, 0);
      }
    }
    __syncthreads();
    #pragma unroll
    for (int mt = 0; mt < 8; ++mt)
      #pragma unroll
      for (int nt = 0; nt < 2; ++nt)
        #pragma unroll
        for (int r = 0; r < 4; ++r)
          Tile[(mt*16 + q*4 + r)*136 + wave*32 + nt*16 + n] = f2h(accv[mt][nt][r]);
    __syncthreads();
    unsigned short* gb = Vt + ((size_t)(b*NH + h))*DK*T_SEQ + t0;
    #pragma unroll
    for (int i = 0; i < 8; ++i) {
      int d = wave*32 + i*4 + srow;
      *(uint4*)(gb + (size_t)d*T_SEQ + scol) = *(const uint4*)&Tile[d*136 + scol];
    }
  }
}

// ---------------------------------------------------------------------------
// Kernel 2a: flash attention SPLIT-K (preferred path).
//  - grid 1024 = (b,h) x qt x kv: each block handles 1024 keys (one half).
//  - KT2=32 tiles, K+V double-buffered: 32 KB LDS -> 3 blocks/CU (reg-capped
//    at 3 waves/SIMD: ~168 unified VGPR+AGPR per wave; launch_bounds(256,3)).
//  - Counted-vmcnt pipeline (4 loads/wave/tile -> vmcnt(4)).
//  - Writes UNNORMALIZED partial O (fp16, rel err 2^-11) + lp (f32);
//    out_proj_split fuses the combine.
// ---------------------------------------------------------------------------
__global__ __launch_bounds__(256, 3) void attn_split_kernel(
    const unsigned short* __restrict__ Qw, const unsigned short* __restrict__ Kw,
    const unsigned short* __restrict__ Vt, unsigned short* __restrict__ O01,
    float* __restrict__ lp01)
{
  __shared__ __align__(16) unsigned short Ks[2][KT2 * DK];   // 2 x 8 KB
  __shared__ __align__(16) unsigned short Vs[2][DK * KT2];   // 2 x 8 KB
  int bid = blockIdx.x;
  int g5 = bid & 31;                       // XCD-clustered (b,h)
  int q2 = bid >> 5;                       // 0..31
  int kv = q2 & 1, qt = q2 >> 1;
  int h = g5 & 7, b = g5 >> 3;
  size_t base = ((size_t)(b * NH + h)) * T_SEQ * DK;
  const unsigned short* Qb = Qw + base;
  const unsigned short* Kb = Kw + base + (size_t)kv * 1024 * DK;
  const unsigned short* Vb = Vt + base + kv * 1024;   // [128][2048], col off
  int t = threadIdx.x, w = t >> 6, lane = t & 63;
  int l31 = lane & 31, l15 = lane & 15, hi = lane >> 5;
  bool hb = (hi != 0);

  short8 qf[8];
  {
    const unsigned short* qr = Qb + (size_t)(qt*QTILE + w*32 + l31) * DK;
    #pragma unroll
    for (int kc = 0; kc < 8; ++kc)
      qf[kc] = *(const short8*)(qr + kc*16 + hi*8);
  }
  floatx16 Oacc[4];
  #pragma unroll
  for (int dt = 0; dt < 4; ++dt)
    #pragma unroll
    for (int r = 0; r < 16; ++r) Oacc[dt][r] = 0.f;
  float lp = 0.f;

  int kkey_lo = lane >> 4;     // K: row-sub (4 rows/inst)
  int kck     = lane & 15;     // K: chunk (16 x 16B per 256B row)
  int vrow    = lane >> 2;     // V: row-sub (16 rows/inst)
  int cv2     = (lane & 3) ^ (vrow & 3);   // V: pre-swizzled chunk (4 x 16B/row)

  #define STAGE_K2(KTI, BUFI)                                                   \
    {                                                                           \
      _Pragma("unroll")                                                         \
      for (int j = 0; j < 2; ++j) {                                             \
        int inst = w*2 + j;                                                     \
        int key = inst*4 + kkey_lo;                                             \
        int ck = kck ^ (key & 15);                                              \
        __builtin_amdgcn_global_load_lds(                                       \
            (gu32_t*)(Kb + ((size_t)((KTI)*KT2 + key))*DK + ck*8),              \
            (lu32_t*)(&Ks[BUFI][inst*512]), 16, 0, 0);                          \
      }                                                                         \
    }

  #define STAGE_V2(KTI, BUFI)                                                   \
    {                                                                           \
      _Pragma("unroll")                                                         \
      for (int j = 0; j < 2; ++j) {                                             \
        int inst = w*2 + j;                                                     \
        int d = inst*16 + vrow;                                                 \
        __builtin_amdgcn_global_load_lds(                                       \
            (gu32_t*)(Vb + (size_t)d*T_SEQ + (KTI)*KT2 + cv2*8),                \
            (lu32_t*)(&Vs[BUFI][inst*512]), 16, 0, 0);                          \
      }                                                                         \
    }

  // 2-deep prologue: 8 stage loads/wave outstanding.
  STAGE_K2(0, 0); STAGE_V2(0, 0);
  STAGE_K2(1, 1); STAGE_V2(1, 1);

  for (int kt = 0; kt < NT2; ++kt) {
    int buf = kt & 1;
    if (kt + 1 < NT2) {
      asm volatile("s_waitcnt vmcnt(4)" ::: "memory");
    } else {
      asm volatile("s_waitcnt vmcnt(0)" ::: "memory");
    }
    __builtin_amdgcn_s_barrier();

    const unsigned short* KsL = &Ks[buf][0];
    const unsigned short* VsL = &Vs[buf][0];

    // QK^T: 32 keys x 32 q-rows; kc-parity split for 2-chain MFMA ILP.
    floatx16 sa, sb;
    #pragma unroll
    for (int r = 0; r < 16; ++r) { sa[r] = 0.f; sb[r] = 0.f; }
    __builtin_amdgcn_s_setprio(1);
    #pragma unroll
    for (int kc = 0; kc < 8; kc += 2) {
      int cp0 = (2*kc + hi) ^ l15;
      int cp1 = (2*(kc+1) + hi) ^ l15;
      short8 ak0 = *(const short8*)&KsL[l31*DK + cp0*8];
      short8 ak1 = *(const short8*)&KsL[l31*DK + cp1*8];
      sa = __builtin_amdgcn_mfma_f32_32x32x16_bf16(ak0, qf[kc],   sa, 0, 0, 0);
      sb = __builtin_amdgcn_mfma_f32_32x32x16_bf16(ak1, qf[kc+1], sb, 0, 0, 0);
    }
    __builtin_amdgcn_s_setprio(0);

    float e[16];
    #pragma unroll
    for (int r = 0; r < 16; ++r) e[r] = EXP2F(sa[r] + sb[r]);
    float s = 0.f;
    #pragma unroll
    for (int r = 0; r < 16; ++r) s += e[r];
    lp += s;
    unsigned p[8];
    #pragma unroll
    for (int i = 0; i < 8; ++i) p[i] = pkh(e[2*i], e[2*i + 1]);
    #pragma unroll
    for (int m = 0; m < 2; ++m) {
      unsigned lo0 = p[4*m], lo1 = p[4*m + 1];
      unsigned up0 = p[4*m + 2], up1 = p[4*m + 3];
      unsigned s0 = hb ? lo0 : up0;
      unsigned s1 = hb ? lo1 : up1;
      unsigned r0 = __shfl_xor(s0, 32, 64);
      unsigned r1 = __shfl_xor(s1, 32, 64);
      union { half8 hv; unsigned u[4]; } fm;
      fm.u[0] = hb ? r0 : lo0;
      fm.u[1] = hb ? r1 : lo1;
      fm.u[2] = hb ? up0 : r0;
      fm.u[3] = hb ? up1 : r1;
      int cp = (2*m + hi) ^ (l31 & 3);   // 4 chunks per 32-t V row
      __builtin_amdgcn_s_setprio(1);
      #pragma unroll
      for (int dt = 0; dt < 4; ++dt) {
        int d = dt*32 + l31;
        half8 bv = *(const half8*)&VsL[d*KT2 + cp*8];
        Oacc[dt] = __builtin_amdgcn_mfma_f32_32x32x16_f16(fm.hv, bv, Oacc[dt], 0, 0, 0);
      }
      __builtin_amdgcn_s_setprio(0);
    }
    __builtin_amdgcn_s_barrier();
    if (kt + 2 < NT2) {
      STAGE_K2(kt + 2, buf);
      STAGE_V2(kt + 2, buf);
    }
  }
  // Partial denominator for q-row l31 (sum both hi halves).
  float lpt = lp + __shfl_xor(lp, 32, 64);

  unsigned short* Op = O01 + (size_t)kv * ((size_t)BATCH * T_SEQ * 1024);
  float* lpp = lp01 + (size_t)kv * ((size_t)BATCH * NH * T_SEQ);
  if (hi == 0)
    lpp[(size_t)(b*NH + h)*T_SEQ + qt*QTILE + w*32 + l31] = lpt;
  #pragma unroll
  for (int dt = 0; dt < 4; ++dt)
    #pragma unroll
    for (int r = 0; r < 16; ++r) {
      int row = (r & 3) + 8*(r >> 2) + 4*hi;
      int trow = qt*QTILE + w*32 + row;
      int col  = h*DK + dt*32 + l31;
      Op[((size_t)b*T_SEQ + trow)*1024 + col] = f2h(Oacc[dt][r]);
    }
}

// ---------------------------------------------------------------------------
// Kernel 2b: flash attention v4 (FALLBACK, verbatim round-5; used only if
// workspace is too small for split partials).
// ---------------------------------------------------------------------------
__global__ __launch_bounds__(256) void attn_kernel(
    const unsigned short* __restrict__ Qw, const unsigned short* __restrict__ Kw,
    const unsigned short* __restrict__ Vt, unsigned short* __restrict__ attn_out)
{
  __shared__ __align__(16) unsigned short Ks[2][KT * DK];
  __shared__ __align__(16) unsigned short Vs[2][DK * KT];
  int bid = blockIdx.x;
  int g5 = bid & 31, qt = bid >> 5;
  int h = g5 & 7, b = g5 >> 3;
  size_t base = ((size_t)(b * NH + h)) * T_SEQ * DK;
  const unsigned short* Qb = Qw + base;
  const unsigned short* Kb = Kw + base;
  const unsigned short* Vb = Vt + base;
  int t = threadIdx.x, w = t >> 6, lane = t & 63;
  int l31 = lane & 31, l15 = lane & 15, hi = lane >> 5;
  bool hb = (hi != 0);

  short8 qf[8];
  {
    const unsigned short* qr = Qb + (size_t)(qt*QTILE + w*32 + l31) * DK;
    #pragma unroll
    for (int kc = 0; kc < 8; ++kc)
      qf[kc] = *(const short8*)(qr + kc*16 + hi*8);
  }
  floatx16 Oacc[4];
  #pragma unroll
  for (int dt = 0; dt < 4; ++dt)
    #pragma unroll
    for (int r = 0; r < 16; ++r) Oacc[dt][r] = 0.f;
  float lp = 0.f;

  int kkey_lo = lane >> 4;
  int kck     = lane & 15;
  int vd_lo   = lane >> 3;
  int vck     = lane & 7;
  int cv      = vck ^ vd_lo;

  #define STAGE_K(KTI, BUFI)                                                    \
    {                                                                           \
      _Pragma("unroll")                                                         \
      for (int j = 0; j < 4; ++j) {                                             \
        int inst = w*4 + j;                                                     \
        int key = inst*4 + kkey_lo;                                             \
        int ck = kck ^ (key & 15);                                              \
        __builtin_amdgcn_global_load_lds(                                       \
            (gu32_t*)(Kb + ((size_t)((KTI)*KT + key))*DK + ck*8),               \
            (lu32_t*)(&Ks[BUFI][inst*512]), 16, 0, 0);                          \
      }                                                                         \
    }

  #define STAGE_V(KTI, BUFI)                                                    \
    {                                                                           \
      _Pragma("unroll")                                                         \
      for (int j = 0; j < 4; ++j) {                                             \
        int inst = w*4 + j;                                                     \
        int d = inst*8 + vd_lo;                                                 \
        __builtin_amdgcn_global_load_lds(                                       \
            (gu32_t*)(Vb + (size_t)d*T_SEQ + (KTI)*KT + cv*8),                  \
            (lu32_t*)(&Vs[BUFI][inst*512]), 16, 0, 0);                          \
      }                                                                         \
    }

  STAGE_K(0, 0); STAGE_V(0, 0);
  STAGE_K(1, 1); STAGE_V(1, 1);

  for (int kt = 0; kt < NT; ++kt) {
    int buf = kt & 1;
    if (kt + 1 < NT) {
      asm volatile("s_waitcnt vmcnt(8)" ::: "memory");
    } else {
      asm volatile("s_waitcnt vmcnt(0)" ::: "memory");
    }
    __builtin_amdgcn_s_barrier();

    const unsigned short* KsL = &Ks[buf][0];
    const unsigned short* VsL = &Vs[buf][0];

    floatx16 st0, st1;
    #pragma unroll
    for (int r = 0; r < 16; ++r) { st0[r] = 0.f; st1[r] = 0.f; }
    __builtin_amdgcn_s_setprio(1);
    #pragma unroll
    for (int kc = 0; kc < 8; ++kc) {
      int cp = (2*kc + hi) ^ l15;
      short8 ak0 = *(const short8*)&KsL[(      l31)*DK + cp*8];
      short8 ak1 = *(const short8*)&KsL[(32 + l31)*DK + cp*8];
      st0 = __builtin_amdgcn_mfma_f32_32x32x16_bf16(ak0, qf[kc], st0, 0, 0, 0);
      st1 = __builtin_amdgcn_mfma_f32_32x32x16_bf16(ak1, qf[kc], st1, 0, 0, 0);
    }
    __builtin_amdgcn_s_setprio(0);
    #pragma unroll
    for (int g = 0; g < 2; ++g) {
      const floatx16& st = g ? st1 : st0;
      float e[16];
      #pragma unroll
      for (int r = 0; r < 16; ++r) e[r] = EXP2F(st[r]);
      float s = 0.f;
      #pragma unroll
      for (int r = 0; r < 16; ++r) s += e[r];
      lp += s;
      unsigned p[8];
      #pragma unroll
      for (int i = 0; i < 8; ++i) p[i] = pkh(e[2*i], e[2*i + 1]);
      #pragma unroll
      for (int m = 0; m < 2; ++m) {
        unsigned lo0 = p[4*m], lo1 = p[4*m + 1];
        unsigned up0 = p[4*m + 2], up1 = p[4*m + 3];
        unsigned s0 = hb ? lo0 : up0;
        unsigned s1 = hb ? lo1 : up1;
        unsigned r0 = __shfl_xor(s0, 32, 64);
        unsigned r1 = __shfl_xor(s1, 32, 64);
        union { half8 hv; unsigned u[4]; } fm;
        fm.u[0] = hb ? r0 : lo0;
        fm.u[1] = hb ? r1 : lo1;
        fm.u[2] = hb ? up0 : r0;
        fm.u[3] = hb ? up1 : r1;
        int cp = (4*g + 2*m + hi) ^ (l31 & 7);
        __builtin_amdgcn_s_setprio(1);
        #pragma unroll
        for (int dt = 0; dt < 4; ++dt) {
          int d = dt*32 + l31;
          half8 bv = *(const half8*)&VsL[d*KT + cp*8];
          Oacc[dt] = __builtin_amdgcn_mfma_f32_32x32x16_f16(fm.hv, bv, Oacc[dt], 0, 0, 0);
        }
        __builtin_amdgcn_s_setprio(0);
      }
    }
    __builtin_amdgcn_s_barrier();
    if (kt + 2 < NT) {
      STAGE_K(kt + 2, buf);
      STAGE_V(kt + 2, buf);
    }
  }
  float lpt = lp + __shfl_xor(lp, 32, 64);
  float rinv = 1.0f / lpt;
  float ri[16];
  #pragma unroll
  for (int r = 0; r < 16; ++r) {
    int row = (r & 3) + 8*(r >> 2) + 4*hi;
    ri[r] = __shfl(rinv, row, 64);
  }
  #pragma unroll
  for (int dt = 0; dt < 4; ++dt)
    #pragma unroll
    for (int r = 0; r < 16; ++r) {
      int row = (r & 3) + 8*(r >> 2) + 4*hi;
      int trow = qt*QTILE + w*32 + row;
      int col  = h*DK + dt*32 + l31;
      attn_out[((size_t)b*T_SEQ + trow)*1024 + col] = f2bf(Oacc[dt][r] * ri[r]);
    }
}

// ---------------------------------------------------------------------------
// Kernel 3a: out_proj with fused split-K combine:
//   A = (O0 + O1) / (lp0 + lp1)  per head-segment, then A @ Wu^T + bu.
// ---------------------------------------------------------------------------
__global__ __launch_bounds__(256) void out_proj_split_kernel(
    const unsigned short* __restrict__ O01, const float* __restrict__ lp01,
    const unsigned short* __restrict__ Wub, const float* __restrict__ bu,
    float* __restrict__ out)
{
  int mb = blockIdx.x * 16;
  int t = threadIdx.x, wave = t >> 6, lane = t & 63;
  int n = lane & 15, q = lane >> 4;
  int nb2 = wave * 32;
  floatx4 acc[2];
  acc[0] = (floatx4){0.f,0.f,0.f,0.f};
  acc[1] = (floatx4){0.f,0.f,0.f,0.f};
  int m = mb + n;
  int bb = m >> 11, tt = m & (T_SEQ - 1);
  const float* l0 = lp01 + (size_t)(bb*NH)*T_SEQ + tt;
  const float* l1 = l0 + (size_t)BATCH*NH*T_SEQ;
  float rinv[8];
  #pragma unroll
  for (int hh = 0; hh < 8; ++hh)
    rinv[hh] = 1.0f / (l0[hh*T_SEQ] + l1[hh*T_SEQ]);

  const unsigned short* ap0 = O01 + (size_t)m * 1024;
  const unsigned short* ap1 = ap0 + (size_t)BATCH * T_SEQ * 1024;
  #pragma unroll
  for (int kc = 0; kc < 32; ++kc) {       // full unroll: head = kc>>2 static
    int ko = kc*32 + q*8;
    float r = rinv[kc >> 2];
    short8 o0 = *(const short8*)(ap0 + ko);
    short8 o1 = *(const short8*)(ap1 + ko);
    union { short8 s; unsigned u[4]; } aw;
    #pragma unroll
    for (int i = 0; i < 4; ++i) {
      float v0 = h2f((unsigned short)o0[2*i])   + h2f((unsigned short)o1[2*i]);
      float v1 = h2f((unsigned short)o0[2*i+1]) + h2f((unsigned short)o1[2*i+1]);
      aw.u[i] = pk2bf(v0 * r, v1 * r);
    }
    #pragma unroll
    for (int cg = 0; cg < 2; ++cg) {
      short8 bw = *(const short8*)(Wub + (size_t)(nb2 + cg*16 + n) * 1024 + ko);
      acc[cg] = __builtin_amdgcn_mfma_f32_16x16x32_bf16(aw.s, bw, acc[cg], 0, 0, 0);
    }
  }
  #pragma unroll
  for (int cg = 0; cg < 2; ++cg)
    #pragma unroll
    for (int r = 0; r < 4; ++r) {
      int mm = mb + q*4 + r;
      int c = nb2 + cg*16 + n;
      out[(size_t)mm * 128 + c] = acc[cg][r] + bu[c];
    }
}

// ---------------------------------------------------------------------------
// Kernel 3b: out_proj (fallback, verbatim).
// ---------------------------------------------------------------------------
__global__ __launch_bounds__(256) void out_proj_kernel(
    const unsigned short* __restrict__ attnb, const unsigned short* __restrict__ Wub,
    const float* __restrict__ bu, float* __restrict__ out)
{
  int mb = blockIdx.x * 16;
  int t = threadIdx.x, wave = t >> 6, lane = t & 63;
  int n = lane & 15, q = lane >> 4;
  int nb2 = wave * 32;
  floatx4 acc[2];
  acc[0] = (floatx4){0.f,0.f,0.f,0.f};
  acc[1] = (floatx4){0.f,0.f,0.f,0.f};
  const unsigned short* ap = attnb + (size_t)(mb + n) * 1024;
  #pragma unroll 8
  for (int kc = 0; kc < 32; ++kc) {
    int ko = kc*32 + q*8;
    short8 a0 = *(const short8*)(ap + ko);
    #pragma unroll
    for (int cg = 0; cg < 2; ++cg) {
      short8 bw = *(const short8*)(Wub + (size_t)(nb2 + cg*16 + n) * 1024 + ko);
      acc[cg] = __builtin_amdgcn_mfma_f32_16x16x32_bf16(a0, bw, acc[cg], 0, 0, 0);
    }
  }
  #pragma unroll
  for (int cg = 0; cg < 2; ++cg)
    #pragma unroll
    for (int r = 0; r < 4; ++r) {
      int m = mb + q*4 + r;
      int c = nb2 + cg*16 + n;
      out[(size_t)m * 128 + c] = acc[cg][r] + bu[c];
    }
}

// ---------------------------------------------------------------------------
extern "C" void kernel_launch(void* const* d_in, const int* in_sizes, int n_in,
                              void* d_out, int out_size, void* d_ws, size_t ws_size,
                              hipStream_t stream) {
  const float* x  = (const float*)d_in[0];
  const float* Wq = (const float*)d_in[1];
  const float* Wk = (const float*)d_in[2];
  const float* Wv = (const float*)d_in[3];
  const float* Wu = (const float*)d_in[4];
  const float* bu = (const float*)d_in[5];
  float* out = (float*)d_out;

  const size_t NE  = (size_t)BATCH * NH * T_SEQ * DK;  // 8,388,608 elems
  const size_t WEL = (size_t)DK * DK * NH;             // 131,072 elems per W
  const size_t LPN = (size_t)BATCH * NH * T_SEQ;       // 65,536 rows
  unsigned short* Qw   = (unsigned short*)d_ws;
  unsigned short* Kw   = Qw + NE;
  unsigned short* Vt   = Kw + NE;
  unsigned short* O0   = Vt + NE;          // split partial 0 / fallback attn
  unsigned short* O1   = O0 + NE;          // split partial 1
  unsigned short* Wqb  = O1 + NE;
  unsigned short* Wkb  = Wqb + WEL;
  unsigned short* Wvb  = Wkb + WEL;
  unsigned short* Wub  = Wvb + WEL;
  float* lp01          = (float*)(Wub + WEL);

  size_t need_split = (5 * NE + 4 * WEL) * sizeof(unsigned short)
                    + 2 * LPN * sizeof(float);
  size_t need_fall  = (4 * NE + 4 * WEL) * sizeof(unsigned short);
  bool split = (ws_size >= need_split);
  if (!split) {
    // fallback layout: W buffers directly after O0 (attn buffer)
    Wqb = O0 + NE; Wkb = Wqb + WEL; Wvb = Wkb + WEL; Wub = Wvb + WEL;
    if (ws_size < need_fall) return;
  }

  convert_w_kernel<<<256, 256, 0, stream>>>(Wq, Wk, Wv, Wu, Wqb, Wkb, Wvb, Wub);
  dim3 g1(8, 64, 3);
  qkv_proj_kernel<<<g1, 256, 0, stream>>>(x, Wqb, Wkb, Wvb, Qw, Kw, Vt);
  if (split) {
    attn_split_kernel<<<BATCH * NH * (T_SEQ / QTILE) * 2, 256, 0, stream>>>(
        Qw, Kw, Vt, O0, lp01);
    out_proj_split_kernel<<<BATCH * T_SEQ / 16, 256, 0, stream>>>(
        O0, lp01, Wub, bu, out);
  } else {
    attn_kernel<<<BATCH * NH * (T_SEQ / QTILE), 256, 0, stream>>>(Qw, Kw, Vt, O0);
    out_proj_kernel<<<BATCH * T_SEQ / 16, 256, 0, stream>>>(O0, Wub, bu, out);
  }
}

// Round 8
// 202.318 us; speedup vs baseline: 1.5659x; 1.0805x over previous
//
#include <hip/hip_runtime.h>
#include <hip/hip_bf16.h>
#include <math.h>

// Problem constants: B=4, T=2048, K(head dim)=128, H=8
#define T_SEQ 2048
#define NH 8
#define DK 128
#define BATCH 4
#define KT 64     // attention KV tile
#define QTILE 128 // Q rows per block (4 waves x 32 rows)
#define NT (T_SEQ / KT)

// Q pre-scale: (1/sqrt(128)) * log2(e)  -> S feeds exp2 directly
#define QSCALE 0.1275174435f

typedef __attribute__((ext_vector_type(8))) short short8;
typedef __attribute__((ext_vector_type(4))) float floatx4;
typedef __attribute__((ext_vector_type(16))) float floatx16;
typedef __attribute__((ext_vector_type(8))) _Float16 half8;

typedef const __attribute__((address_space(1))) unsigned int gu32_t;
typedef __attribute__((address_space(3))) unsigned int lu32_t;

#if defined(__has_builtin)
#if __has_builtin(__builtin_amdgcn_exp2f)
#define EXP2F(x) __builtin_amdgcn_exp2f(x)
#endif
#endif
#ifndef EXP2F
#define EXP2F(x) exp2f(x)
#endif

__device__ __forceinline__ unsigned short f2bf(float f) {
  union { float f; unsigned u; } v; v.f = f;
  unsigned u = v.u;
  return (unsigned short)((u + 0x7fffu + ((u >> 16) & 1u)) >> 16);  // RNE
}

__device__ __forceinline__ unsigned short f2h(float f) {
  union { _Float16 h; unsigned short u; } v; v.h = (_Float16)f;
  return v.u;
}

__device__ __forceinline__ unsigned pk2bf(float a, float b) {
  __hip_bfloat162 h = __float22bfloat162_rn(make_float2(a, b));
  return *(unsigned*)&h;   // low 16 = a, high 16 = b
}

__device__ __forceinline__ unsigned pkh(float a, float b) {
  union { _Float16 h[2]; unsigned u; } v;
  v.h[0] = (_Float16)a; v.h[1] = (_Float16)b;
  return v.u;
}

// ---------------------------------------------------------------------------
// Kernel 1: fused QKV projection + Wu conversion.
// grid (8, 64, 4):
//   z=0..2: Q/K/V projection. W tile converted fp32 -> bf16 INLINE into LDS
//           (XOR-swizzled write; replaces the former convert_w round-trip).
//   z=3:    Wu fp32 -> bf16 (first 128 blocks of the slice; rest exit).
// ---------------------------------------------------------------------------
__global__ __launch_bounds__(256) void qkv_proj_kernel(
    const float* __restrict__ x,
    const float* __restrict__ Wq, const float* __restrict__ Wk,
    const float* __restrict__ Wv, const float* __restrict__ Wu,
    unsigned short* __restrict__ Qw, unsigned short* __restrict__ Kw,
    unsigned short* __restrict__ Vt, unsigned short* __restrict__ Wub)
{
  __shared__ __align__(16) unsigned short Tile[128 * 136];   // 34.8 KB
  int w3 = blockIdx.z;             // 0=Q 1=K 2=V 3=Wu-convert
  int t = threadIdx.x;

  if (w3 == 3) {
    int cb = blockIdx.y * 8 + blockIdx.x;    // 0..511
    if (cb < 128) {
      size_t off = (size_t)cb * 1024 + (size_t)t * 4;
      float4 a = *(const float4*)(Wu + off);
      *(uint2*)(Wub + off) = make_uint2(pk2bf(a.x, a.y), pk2bf(a.z, a.w));
    }
    return;
  }

  int h  = blockIdx.x;             // head = col block (128 cols)
  int nb = h * 128;
  int mb = blockIdx.y * 128;       // row base within 8192
  int b = mb >> 11, t0 = mb & (T_SEQ - 1);
  int wave = t >> 6, lane = t & 63;
  int n = lane & 15, q = lane >> 4;
  int srow = lane >> 4;            // readback row-subindex
  int scol = (lane & 15) * 8;      // readback col (shorts)

  // Inline W convert: rows nb..nb+127 (output cols), k = 0..127.
  // Each thread: half a row (8 chunks of 16B), written XOR-swizzled
  // (chunk c of row r lands at slot c ^ (r&15)) so the MFMA-phase
  // ds_read_b128 at slot (kc*4+q)^n retrieves chunk kc*4+q conflict-lite.
  {
    const float* Wf = (w3 == 0) ? Wq : ((w3 == 1) ? Wk : Wv);
    float s = (w3 == 0) ? QSCALE : 1.0f;
    int crow = t >> 1, cc8 = (t & 1) * 8;
    const float* Wr = Wf + (size_t)(nb + crow) * DK + cc8 * 8;
    #pragma unroll
    for (int i = 0; i < 8; ++i) {
      float4 f0 = *(const float4*)(Wr + i*8);
      float4 f1 = *(const float4*)(Wr + i*8 + 4);
      int slot = (cc8 + i) ^ (crow & 15);
      union { uint4 u4; unsigned u[4]; } pk;
      pk.u[0] = pk2bf(f0.x*s, f0.y*s); pk.u[1] = pk2bf(f0.z*s, f0.w*s);
      pk.u[2] = pk2bf(f1.x*s, f1.y*s); pk.u[3] = pk2bf(f1.z*s, f1.w*s);
      *(uint4*)&Tile[crow*DK + slot*8] = pk.u4;
    }
  }

  // x A-fragments for this wave's 32 rows (fp32 -> bf16 in regs)
  short8 xa[2][4];
  #pragma unroll
  for (int rg = 0; rg < 2; ++rg) {
    const float* xr = x + (size_t)(mb + wave*32 + rg*16 + n) * DK;
    #pragma unroll
    for (int kc = 0; kc < 4; ++kc) {
      float4 f0 = *(const float4*)(xr + kc*32 + q*8);
      float4 f1 = *(const float4*)(xr + kc*32 + q*8 + 4);
      union { short8 s; unsigned u[4]; } pk;
      pk.u[0] = pk2bf(f0.x, f0.y); pk.u[1] = pk2bf(f0.z, f0.w);
      pk.u[2] = pk2bf(f1.x, f1.y); pk.u[3] = pk2bf(f1.z, f1.w);
      xa[rg][kc] = pk.s;
    }
  }

  __syncthreads();   // W converted & written

  if (w3 < 2) {
    floatx4 acc[2][8];
    #pragma unroll
    for (int rg = 0; rg < 2; ++rg)
      #pragma unroll
      for (int cg = 0; cg < 8; ++cg)
        acc[rg][cg] = (floatx4){0.f, 0.f, 0.f, 0.f};
    #pragma unroll
    for (int kc = 0; kc < 4; ++kc) {
      int p = ((kc*4 + q) ^ n) * 8;       // swizzled chunk (shorts)
      #pragma unroll
      for (int cg = 0; cg < 8; ++cg) {
        short8 bk = *(const short8*)&Tile[(cg*16 + n)*DK + p];
        acc[0][cg] = __builtin_amdgcn_mfma_f32_16x16x32_bf16(xa[0][kc], bk, acc[0][cg], 0, 0, 0);
        acc[1][cg] = __builtin_amdgcn_mfma_f32_16x16x32_bf16(xa[1][kc], bk, acc[1][cg], 0, 0, 0);
      }
    }
    __syncthreads();   // all W reads done before C overwrites Tile
    #pragma unroll
    for (int rg = 0; rg < 2; ++rg)
      #pragma unroll
      for (int cg = 0; cg < 8; ++cg)
        #pragma unroll
        for (int r = 0; r < 4; ++r)
          Tile[(wave*32 + rg*16 + q*4 + r)*136 + cg*16 + n] = f2bf(acc[rg][cg][r]);
    __syncthreads();
    unsigned short* gb = ((w3 == 0) ? Qw : Kw) +
        (((size_t)(b*NH + h))*T_SEQ + t0)*DK;
    #pragma unroll
    for (int i = 0; i < 8; ++i) {
      int row = wave*32 + i*4 + srow;
      *(uint4*)(gb + (size_t)row*DK + scol) = *(const uint4*)&Tile[row*136 + scol];
    }
  } else {
    // V: transposed C-tile (rows = d, cols = tt) via swapped operands
    floatx4 accv[8][2];
    #pragma unroll
    for (int mt = 0; mt < 8; ++mt)
      #pragma unroll
      for (int nt = 0; nt < 2; ++nt)
        accv[mt][nt] = (floatx4){0.f, 0.f, 0.f, 0.f};
    #pragma unroll
    for (int kc = 0; kc < 4; ++kc) {
      int p = ((kc*4 + q) ^ n) * 8;
      #pragma unroll
      for (int mt = 0; mt < 8; ++mt) {
        short8 wa = *(const short8*)&Tile[(mt*16 + n)*DK + p];
        accv[mt][0] = __builtin_amdgcn_mfma_f32_16x16x32_bf16(wa, xa[0][kc], accv[mt][0], 0, 0, 0);
        accv[mt][1] = __builtin_amdgcn_mfma_f32_16x16x32_bf16(wa, xa[1][kc], accv[mt][1], 0, 0, 0);
      }
    }
    __syncthreads();
    #pragma unroll
    for (int mt = 0; mt < 8; ++mt)
      #pragma unroll
      for (int nt = 0; nt < 2; ++nt)
        #pragma unroll
        for (int r = 0; r < 4; ++r)
          Tile[(mt*16 + q*4 + r)*136 + wave*32 + nt*16 + n] = f2h(accv[mt][nt][r]);
    __syncthreads();
    unsigned short* gb = Vt + ((size_t)(b*NH + h))*DK*T_SEQ + t0;
    #pragma unroll
    for (int i = 0; i < 8; ++i) {
      int d = wave*32 + i*4 + srow;
      *(uint4*)(gb + (size_t)d*T_SEQ + scol) = *(const uint4*)&Tile[d*136 + scol];
    }
  }
}

// ---------------------------------------------------------------------------
// Kernel 2: flash attention v4 (round-5 verbatim, best measured: 89.5 us).
// Counted-vmcnt pipeline; K+V double-buffered; XCD-cluster remap; setprio.
// ---------------------------------------------------------------------------
__global__ __launch_bounds__(256) void attn_kernel(
    const unsigned short* __restrict__ Qw, const unsigned short* __restrict__ Kw,
    const unsigned short* __restrict__ Vt, unsigned short* __restrict__ attn_out)
{
  __shared__ __align__(16) unsigned short Ks[2][KT * DK];   // 2 x 16 KB
  __shared__ __align__(16) unsigned short Vs[2][DK * KT];   // 2 x 16 KB
  int bid = blockIdx.x;
  int g5 = bid & 31, qt = bid >> 5;       // XCD-clustered: (b,h) fixed mod 32
  int h = g5 & 7, b = g5 >> 3;
  size_t base = ((size_t)(b * NH + h)) * T_SEQ * DK;
  const unsigned short* Qb = Qw + base;
  const unsigned short* Kb = Kw + base;
  const unsigned short* Vb = Vt + base;   // [128][2048] fp16
  int t = threadIdx.x, w = t >> 6, lane = t & 63;
  int l31 = lane & 31, l15 = lane & 15, hi = lane >> 5;
  bool hb = (hi != 0);

  short8 qf[8];
  {
    const unsigned short* qr = Qb + (size_t)(qt*QTILE + w*32 + l31) * DK;
    #pragma unroll
    for (int kc = 0; kc < 8; ++kc)
      qf[kc] = *(const short8*)(qr + kc*16 + hi*8);
  }
  floatx16 Oacc[4];
  #pragma unroll
  for (int dt = 0; dt < 4; ++dt)
    #pragma unroll
    for (int r = 0; r < 16; ++r) Oacc[dt][r] = 0.f;
  float lp = 0.f;

  int kkey_lo = lane >> 4;
  int kck     = lane & 15;
  int vd_lo   = lane >> 3;
  int vck     = lane & 7;
  int cv      = vck ^ vd_lo;

  #define STAGE_K(KTI, BUFI)                                                    \
    {                                                                           \
      _Pragma("unroll")                                                         \
      for (int j = 0; j < 4; ++j) {                                             \
        int inst = w*4 + j;                                                     \
        int key = inst*4 + kkey_lo;                                             \
        int ck = kck ^ (key & 15);                                              \
        __builtin_amdgcn_global_load_lds(                                       \
            (gu32_t*)(Kb + ((size_t)((KTI)*KT + key))*DK + ck*8),               \
            (lu32_t*)(&Ks[BUFI][inst*512]), 16, 0, 0);                          \
      }                                                                         \
    }

  #define STAGE_V(KTI, BUFI)                                                    \
    {                                                                           \
      _Pragma("unroll")                                                         \
      for (int j = 0; j < 4; ++j) {                                             \
        int inst = w*4 + j;                                                     \
        int d = inst*8 + vd_lo;                                                 \
        __builtin_amdgcn_global_load_lds(                                       \
            (gu32_t*)(Vb + (size_t)d*T_SEQ + (KTI)*KT + cv*8),                  \
            (lu32_t*)(&Vs[BUFI][inst*512]), 16, 0, 0);                          \
      }                                                                         \
    }

  STAGE_K(0, 0); STAGE_V(0, 0);
  STAGE_K(1, 1); STAGE_V(1, 1);

  for (int kt = 0; kt < NT; ++kt) {
    int buf = kt & 1;
    if (kt + 1 < NT) {
      asm volatile("s_waitcnt vmcnt(8)" ::: "memory");
    } else {
      asm volatile("s_waitcnt vmcnt(0)" ::: "memory");
    }
    __builtin_amdgcn_s_barrier();

    const unsigned short* KsL = &Ks[buf][0];
    const unsigned short* VsL = &Vs[buf][0];

    floatx16 st0, st1;
    #pragma unroll
    for (int r = 0; r < 16; ++r) { st0[r] = 0.f; st1[r] = 0.f; }
    __builtin_amdgcn_s_setprio(1);
    #pragma unroll
    for (int kc = 0; kc < 8; ++kc) {
      int cp = (2*kc + hi) ^ l15;
      short8 ak0 = *(const short8*)&KsL[(      l31)*DK + cp*8];
      short8 ak1 = *(const short8*)&KsL[(32 + l31)*DK + cp*8];
      st0 = __builtin_amdgcn_mfma_f32_32x32x16_bf16(ak0, qf[kc], st0, 0, 0, 0);
      st1 = __builtin_amdgcn_mfma_f32_32x32x16_bf16(ak1, qf[kc], st1, 0, 0, 0);
    }
    __builtin_amdgcn_s_setprio(0);
    #pragma unroll
    for (int g = 0; g < 2; ++g) {
      const floatx16& st = g ? st1 : st0;
      float e[16];
      #pragma unroll
      for (int r = 0; r < 16; ++r) e[r] = EXP2F(st[r]);
      float s = 0.f;
      #pragma unroll
      for (int r = 0; r < 16; ++r) s += e[r];
      lp += s;
      unsigned p[8];
      #pragma unroll
      for (int i = 0; i < 8; ++i) p[i] = pkh(e[2*i], e[2*i + 1]);
      #pragma unroll
      for (int m = 0; m < 2; ++m) {
        unsigned lo0 = p[4*m], lo1 = p[4*m + 1];
        unsigned up0 = p[4*m + 2], up1 = p[4*m + 3];
        unsigned s0 = hb ? lo0 : up0;
        unsigned s1 = hb ? lo1 : up1;
        unsigned r0 = __shfl_xor(s0, 32, 64);
        unsigned r1 = __shfl_xor(s1, 32, 64);
        union { half8 hv; unsigned u[4]; } fm;
        fm.u[0] = hb ? r0 : lo0;
        fm.u[1] = hb ? r1 : lo1;
        fm.u[2] = hb ? up0 : r0;
        fm.u[3] = hb ? up1 : r1;
        int cp = (4*g + 2*m + hi) ^ (l31 & 7);
        __builtin_amdgcn_s_setprio(1);
        #pragma unroll
        for (int dt = 0; dt < 4; ++dt) {
          int d = dt*32 + l31;
          half8 bv = *(const half8*)&VsL[d*KT + cp*8];
          Oacc[dt] = __builtin_amdgcn_mfma_f32_32x32x16_f16(fm.hv, bv, Oacc[dt], 0, 0, 0);
        }
        __builtin_amdgcn_s_setprio(0);
      }
    }
    __builtin_amdgcn_s_barrier();
    if (kt + 2 < NT) {
      STAGE_K(kt + 2, buf);
      STAGE_V(kt + 2, buf);
    }
  }
  float lpt = lp + __shfl_xor(lp, 32, 64);
  float rinv = 1.0f / lpt;
  float ri[16];
  #pragma unroll
  for (int r = 0; r < 16; ++r) {
    int row = (r & 3) + 8*(r >> 2) + 4*hi;
    ri[r] = __shfl(rinv, row, 64);
  }
  #pragma unroll
  for (int dt = 0; dt < 4; ++dt)
    #pragma unroll
    for (int r = 0; r < 16; ++r) {
      int row = (r & 3) + 8*(r >> 2) + 4*hi;
      int trow = qt*QTILE + w*32 + row;
      int col  = h*DK + dt*32 + l31;
      attn_out[((size_t)b*T_SEQ + trow)*1024 + col] = f2bf(Oacc[dt][r] * ri[r]);
    }
}

// ---------------------------------------------------------------------------
// Kernel 3: out = attn(8192,1024)bf16 @ Wu^T + bu (round-5 verbatim).
// ---------------------------------------------------------------------------
__global__ __launch_bounds__(256) void out_proj_kernel(
    const unsigned short* __restrict__ attnb, const unsigned short* __restrict__ Wub,
    const float* __restrict__ bu, float* __restrict__ out)
{
  int mb = blockIdx.x * 16;
  int t = threadIdx.x, wave = t >> 6, lane = t & 63;
  int n = lane & 15, q = lane >> 4;
  int nb2 = wave * 32;
  floatx4 acc[2];
  acc[0] = (floatx4){0.f,0.f,0.f,0.f};
  acc[1] = (floatx4){0.f,0.f,0.f,0.f};
  const unsigned short* ap = attnb + (size_t)(mb + n) * 1024;
  #pragma unroll 8
  for (int kc = 0; kc < 32; ++kc) {
    int ko = kc*32 + q*8;
    short8 a0 = *(const short8*)(ap + ko);
    #pragma unroll
    for (int cg = 0; cg < 2; ++cg) {
      short8 bw = *(const short8*)(Wub + (size_t)(nb2 + cg*16 + n) * 1024 + ko);
      acc[cg] = __builtin_amdgcn_mfma_f32_16x16x32_bf16(a0, bw, acc[cg], 0, 0, 0);
    }
  }
  #pragma unroll
  for (int cg = 0; cg < 2; ++cg)
    #pragma unroll
    for (int r = 0; r < 4; ++r) {
      int m = mb + q*4 + r;
      int c = nb2 + cg*16 + n;
      out[(size_t)m * 128 + c] = acc[cg][r] + bu[c];
    }
}

// ---------------------------------------------------------------------------
extern "C" void kernel_launch(void* const* d_in, const int* in_sizes, int n_in,
                              void* d_out, int out_size, void* d_ws, size_t ws_size,
                              hipStream_t stream) {
  const float* x  = (const float*)d_in[0];
  const float* Wq = (const float*)d_in[1];
  const float* Wk = (const float*)d_in[2];
  const float* Wv = (const float*)d_in[3];
  const float* Wu = (const float*)d_in[4];
  const float* bu = (const float*)d_in[5];
  float* out = (float*)d_out;

  const size_t NE  = (size_t)BATCH * NH * T_SEQ * DK;  // 8,388,608 elems
  const size_t WEL = (size_t)DK * DK * NH;             // 131,072 elems
  unsigned short* Qw   = (unsigned short*)d_ws;
  unsigned short* Kw   = Qw + NE;
  unsigned short* Vt   = Kw + NE;
  unsigned short* attn = Vt + NE;
  unsigned short* Wub  = attn + NE;
  if (ws_size < (4 * NE + WEL) * sizeof(unsigned short)) return;

  dim3 g1(8, 64, 4);
  qkv_proj_kernel<<<g1, 256, 0, stream>>>(x, Wq, Wk, Wv, Wu, Qw, Kw, Vt, Wub);
  attn_kernel<<<BATCH * NH * (T_SEQ / QTILE), 256, 0, stream>>>(Qw, Kw, Vt, attn);
  out_proj_kernel<<<BATCH * T_SEQ / 16, 256, 0, stream>>>(attn, Wub, bu, out);
}

// Round 10
// 188.926 us; speedup vs baseline: 1.6768x; 1.0709x over previous
//
#include <hip/hip_runtime.h>
#include <hip/hip_bf16.h>
#include <math.h>

// Problem constants: B=4, T=2048, K(head dim)=128, H=8
#define T_SEQ 2048
#define NH 8
#define DK 128
#define BATCH 4
#define KT 64     // attention KV tile
#define QTILE 128 // Q rows per block (4 waves x 32 rows)
#define NT (T_SEQ / KT)

// Q pre-scale: (1/sqrt(128)) * log2(e)  -> S feeds exp2 directly
#define QSCALE 0.1275174435f

typedef __attribute__((ext_vector_type(8))) short short8;
typedef __attribute__((ext_vector_type(4))) float floatx4;
typedef __attribute__((ext_vector_type(16))) float floatx16;
typedef __attribute__((ext_vector_type(8))) _Float16 half8;

typedef const __attribute__((address_space(1))) unsigned int gu32_t;
typedef __attribute__((address_space(3))) unsigned int lu32_t;

#if defined(__has_builtin)
#if __has_builtin(__builtin_amdgcn_exp2f)
#define EXP2F(x) __builtin_amdgcn_exp2f(x)
#endif
#endif
#ifndef EXP2F
#define EXP2F(x) exp2f(x)
#endif

__device__ __forceinline__ unsigned short f2bf(float f) {
  union { float f; unsigned u; } v; v.f = f;
  unsigned u = v.u;
  return (unsigned short)((u + 0x7fffu + ((u >> 16) & 1u)) >> 16);  // RNE
}

__device__ __forceinline__ unsigned short f2h(float f) {
  union { _Float16 h; unsigned short u; } v; v.h = (_Float16)f;
  return v.u;
}

__device__ __forceinline__ unsigned pk2bf(float a, float b) {
  __hip_bfloat162 h = __float22bfloat162_rn(make_float2(a, b));
  return *(unsigned*)&h;   // low 16 = a, high 16 = b
}

__device__ __forceinline__ unsigned pkh(float a, float b) {
  union { _Float16 h[2]; unsigned u; } v;
  v.h[0] = (_Float16)a; v.h[1] = (_Float16)b;
  return v.u;
}

// ---------------------------------------------------------------------------
// Kernel 0: one-time fp32 -> bf16 conversion of Wq(xQSCALE), Wk, Wv, Wu AND x.
// grid = 768 blocks x 256 thr, 8 elems/thread:
//   blocks   0..255 -> the four W matrices (64 blocks each, 131072 elems)
//   blocks 256..767 -> x (1,048,576 elems)
// ---------------------------------------------------------------------------
__global__ __launch_bounds__(256) void convert_kernel(
    const float* __restrict__ x,
    const float* __restrict__ Wq, const float* __restrict__ Wk,
    const float* __restrict__ Wv, const float* __restrict__ Wu,
    unsigned short* __restrict__ xb,
    unsigned short* __restrict__ Wqb, unsigned short* __restrict__ Wkb,
    unsigned short* __restrict__ Wvb, unsigned short* __restrict__ Wub)
{
  int bidx = blockIdx.x;
  const float* src;
  unsigned short* dst;
  float s = 1.0f;
  size_t off;
  if (bidx < 256) {
    int which = bidx >> 6;
    src = (which == 0) ? Wq : (which == 1) ? Wk : (which == 2) ? Wv : Wu;
    dst = (which == 0) ? Wqb : (which == 1) ? Wkb : (which == 2) ? Wvb : Wub;
    if (which == 0) s = QSCALE;
    off = ((size_t)(bidx & 63) * 256 + threadIdx.x) * 8;
  } else {
    src = x; dst = xb;
    off = ((size_t)(bidx - 256) * 256 + threadIdx.x) * 8;
  }
  float4 a = *(const float4*)(src + off);
  float4 c = *(const float4*)(src + off + 4);
  uint4 o;
  o.x = pk2bf(a.x * s, a.y * s);
  o.y = pk2bf(a.z * s, a.w * s);
  o.z = pk2bf(c.x * s, c.y * s);
  o.w = pk2bf(c.z * s, c.w * s);
  *(uint4*)(dst + off) = o;
}

// ---------------------------------------------------------------------------
// Kernel 1: fused QKV projection (round-5 structure; x loaded as bf16).
// ---------------------------------------------------------------------------
__global__ __launch_bounds__(256) void qkv_proj_kernel(
    const unsigned short* __restrict__ xb,
    const unsigned short* __restrict__ Wqb,
    const unsigned short* __restrict__ Wkb,
    const unsigned short* __restrict__ Wvb,
    unsigned short* __restrict__ Qw, unsigned short* __restrict__ Kw,
    unsigned short* __restrict__ Vt)
{
  __shared__ __align__(16) unsigned short Tile[128 * 136];   // 34.8 KB
  int h  = blockIdx.x;             // head = col block (128 cols)
  int nb = h * 128;
  int mb = blockIdx.y * 128;       // row base within 8192
  int w3 = blockIdx.z;             // 0=Q 1=K 2=V
  int b = mb >> 11, t0 = mb & (T_SEQ - 1);
  int t = threadIdx.x, wave = t >> 6, lane = t & 63;
  int n = lane & 15, q = lane >> 4;
  int srow = lane >> 4;            // readback row-subindex
  int scol = (lane & 15) * 8;      // readback col (shorts)

  const unsigned short* Wsrc = (w3 == 0) ? Wqb : ((w3 == 1) ? Wkb : Wvb);
  const unsigned short* Wb = Wsrc + (size_t)nb * DK;
  #pragma unroll
  for (int j = 0; j < 8; ++j) {
    int inst = wave * 8 + j;              // 32 insts cover 128 rows
    int row = inst * 4 + (lane >> 4);     // 4 rows per inst
    int ck = (lane & 15) ^ (row & 15);    // pre-swizzled source chunk
    __builtin_amdgcn_global_load_lds(
        (gu32_t*)(Wb + (size_t)row * DK + ck * 8),
        (lu32_t*)(&Tile[inst * 512]), 16, 0, 0);
  }

  // x A-fragments for this wave's 32 rows: direct bf16 short8 loads.
  short8 xa[2][4];
  #pragma unroll
  for (int rg = 0; rg < 2; ++rg) {
    const unsigned short* xr = xb + (size_t)(mb + wave*32 + rg*16 + n) * DK;
    #pragma unroll
    for (int kc = 0; kc < 4; ++kc)
      xa[rg][kc] = *(const short8*)(xr + kc*32 + q*8);
  }

  __syncthreads();   // W staged

  if (w3 < 2) {
    floatx4 acc[2][8];
    #pragma unroll
    for (int rg = 0; rg < 2; ++rg)
      #pragma unroll
      for (int cg = 0; cg < 8; ++cg)
        acc[rg][cg] = (floatx4){0.f, 0.f, 0.f, 0.f};
    #pragma unroll
    for (int kc = 0; kc < 4; ++kc) {
      int p = ((kc*4 + q) ^ n) * 8;       // swizzled chunk (shorts)
      #pragma unroll
      for (int cg = 0; cg < 8; ++cg) {
        short8 bk = *(const short8*)&Tile[(cg*16 + n)*DK + p];
        acc[0][cg] = __builtin_amdgcn_mfma_f32_16x16x32_bf16(xa[0][kc], bk, acc[0][cg], 0, 0, 0);
        acc[1][cg] = __builtin_amdgcn_mfma_f32_16x16x32_bf16(xa[1][kc], bk, acc[1][cg], 0, 0, 0);
      }
    }
    __syncthreads();   // all W reads done before C overwrites Tile
    #pragma unroll
    for (int rg = 0; rg < 2; ++rg)
      #pragma unroll
      for (int cg = 0; cg < 8; ++cg)
        #pragma unroll
        for (int r = 0; r < 4; ++r)
          Tile[(wave*32 + rg*16 + q*4 + r)*136 + cg*16 + n] = f2bf(acc[rg][cg][r]);
    __syncthreads();
    unsigned short* gb = ((w3 == 0) ? Qw : Kw) +
        (((size_t)(b*NH + h))*T_SEQ + t0)*DK;
    #pragma unroll
    for (int i = 0; i < 8; ++i) {
      int row = wave*32 + i*4 + srow;
      *(uint4*)(gb + (size_t)row*DK + scol) = *(const uint4*)&Tile[row*136 + scol];
    }
  } else {
    // V: transposed C-tile (rows = d, cols = tt) via swapped operands
    floatx4 accv[8][2];
    #pragma unroll
    for (int mt = 0; mt < 8; ++mt)
      #pragma unroll
      for (int nt = 0; nt < 2; ++nt)
        accv[mt][nt] = (floatx4){0.f, 0.f, 0.f, 0.f};
    #pragma unroll
    for (int kc = 0; kc < 4; ++kc) {
      int p = ((kc*4 + q) ^ n) * 8;
      #pragma unroll
      for (int mt = 0; mt < 8; ++mt) {
        short8 wa = *(const short8*)&Tile[(mt*16 + n)*DK + p];
        accv[mt][0] = __builtin_amdgcn_mfma_f32_16x16x32_bf16(wa, xa[0][kc], accv[mt][0], 0, 0, 0);
        accv[mt][1] = __builtin_amdgcn_mfma_f32_16x16x32_bf16(wa, xa[1][kc], accv[mt][1], 0, 0, 0);
      }
    }
    __syncthreads();
    #pragma unroll
    for (int mt = 0; mt < 8; ++mt)
      #pragma unroll
      for (int nt = 0; nt < 2; ++nt)
        #pragma unroll
        for (int r = 0; r < 4; ++r)
          Tile[(mt*16 + q*4 + r)*136 + wave*32 + nt*16 + n] = f2h(accv[mt][nt][r]);
    __syncthreads();
    unsigned short* gb = Vt + ((size_t)(b*NH + h))*DK*T_SEQ + t0;
    #pragma unroll
    for (int i = 0; i < 8; ++i) {
      int d = wave*32 + i*4 + srow;
      *(uint4*)(gb + (size_t)d*T_SEQ + scol) = *(const uint4*)&Tile[d*136 + scol];
    }
  }
}

// ---------------------------------------------------------------------------
// Kernel 2: flash attention v4 (round-5 verbatim, best measured: 89.5 us).
// ---------------------------------------------------------------------------
__global__ __launch_bounds__(256) void attn_kernel(
    const unsigned short* __restrict__ Qw, const unsigned short* __restrict__ Kw,
    const unsigned short* __restrict__ Vt, unsigned short* __restrict__ attn_out)
{
  __shared__ __align__(16) unsigned short Ks[2][KT * DK];   // 2 x 16 KB
  __shared__ __align__(16) unsigned short Vs[2][DK * KT];   // 2 x 16 KB
  int bid = blockIdx.x;
  int g5 = bid & 31, qt = bid >> 5;       // XCD-clustered: (b,h) fixed mod 32
  int h = g5 & 7, b = g5 >> 3;
  size_t base = ((size_t)(b * NH + h)) * T_SEQ * DK;
  const unsigned short* Qb = Qw + base;
  const unsigned short* Kb = Kw + base;
  const unsigned short* Vb = Vt + base;   // [128][2048] fp16
  int t = threadIdx.x, w = t >> 6, lane = t & 63;
  int l31 = lane & 31, l15 = lane & 15, hi = lane >> 5;
  bool hb = (hi != 0);

  short8 qf[8];
  {
    const unsigned short* qr = Qb + (size_t)(qt*QTILE + w*32 + l31) * DK;
    #pragma unroll
    for (int kc = 0; kc < 8; ++kc)
      qf[kc] = *(const short8*)(qr + kc*16 + hi*8);
  }
  floatx16 Oacc[4];
  #pragma unroll
  for (int dt = 0; dt < 4; ++dt)
    #pragma unroll
    for (int r = 0; r < 16; ++r) Oacc[dt][r] = 0.f;
  float lp = 0.f;

  int kkey_lo = lane >> 4;
  int kck     = lane & 15;
  int vd_lo   = lane >> 3;
  int vck     = lane & 7;
  int cv      = vck ^ vd_lo;

  #define STAGE_K(KTI, BUFI)                                                    \
    {                                                                           \
      _Pragma("unroll")                                                         \
      for (int j = 0; j < 4; ++j) {                                             \
        int inst = w*4 + j;                                                     \
        int key = inst*4 + kkey_lo;                                             \
        int ck = kck ^ (key & 15);                                              \
        __builtin_amdgcn_global_load_lds(                                       \
            (gu32_t*)(Kb + ((size_t)((KTI)*KT + key))*DK + ck*8),               \
            (lu32_t*)(&Ks[BUFI][inst*512]), 16, 0, 0);                          \
      }                                                                         \
    }

  #define STAGE_V(KTI, BUFI)                                                    \
    {                                                                           \
      _Pragma("unroll")                                                         \
      for (int j = 0; j < 4; ++j) {                                             \
        int inst = w*4 + j;                                                     \
        int d = inst*8 + vd_lo;                                                 \
        __builtin_amdgcn_global_load_lds(                                       \
            (gu32_t*)(Vb + (size_t)d*T_SEQ + (KTI)*KT + cv*8),                  \
            (lu32_t*)(&Vs[BUFI][inst*512]), 16, 0, 0);                          \
      }                                                                         \
    }

  STAGE_K(0, 0); STAGE_V(0, 0);
  STAGE_K(1, 1); STAGE_V(1, 1);

  for (int kt = 0; kt < NT; ++kt) {
    int buf = kt & 1;
    if (kt + 1 < NT) {
      asm volatile("s_waitcnt vmcnt(8)" ::: "memory");
    } else {
      asm volatile("s_waitcnt vmcnt(0)" ::: "memory");
    }
    __builtin_amdgcn_s_barrier();

    const unsigned short* KsL = &Ks[buf][0];
    const unsigned short* VsL = &Vs[buf][0];

    floatx16 st0, st1;
    #pragma unroll
    for (int r = 0; r < 16; ++r) { st0[r] = 0.f; st1[r] = 0.f; }
    __builtin_amdgcn_s_setprio(1);
    #pragma unroll
    for (int kc = 0; kc < 8; ++kc) {
      int cp = (2*kc + hi) ^ l15;
      short8 ak0 = *(const short8*)&KsL[(      l31)*DK + cp*8];
      short8 ak1 = *(const short8*)&KsL[(32 + l31)*DK + cp*8];
      st0 = __builtin_amdgcn_mfma_f32_32x32x16_bf16(ak0, qf[kc], st0, 0, 0, 0);
      st1 = __builtin_amdgcn_mfma_f32_32x32x16_bf16(ak1, qf[kc], st1, 0, 0, 0);
    }
    __builtin_amdgcn_s_setprio(0);
    #pragma unroll
    for (int g = 0; g < 2; ++g) {
      const floatx16& st = g ? st1 : st0;
      float e[16];
      #pragma unroll
      for (int r = 0; r < 16; ++r) e[r] = EXP2F(st[r]);
      float s = 0.f;
      #pragma unroll
      for (int r = 0; r < 16; ++r) s += e[r];
      lp += s;
      unsigned p[8];
      #pragma unroll
      for (int i = 0; i < 8; ++i) p[i] = pkh(e[2*i], e[2*i + 1]);
      #pragma unroll
      for (int m = 0; m < 2; ++m) {
        unsigned lo0 = p[4*m], lo1 = p[4*m + 1];
        unsigned up0 = p[4*m + 2], up1 = p[4*m + 3];
        unsigned s0 = hb ? lo0 : up0;
        unsigned s1 = hb ? lo1 : up1;
        unsigned r0 = __shfl_xor(s0, 32, 64);
        unsigned r1 = __shfl_xor(s1, 32, 64);
        union { half8 hv; unsigned u[4]; } fm;
        fm.u[0] = hb ? r0 : lo0;
        fm.u[1] = hb ? r1 : lo1;
        fm.u[2] = hb ? up0 : r0;
        fm.u[3] = hb ? up1 : r1;
        int cp = (4*g + 2*m + hi) ^ (l31 & 7);
        __builtin_amdgcn_s_setprio(1);
        #pragma unroll
        for (int dt = 0; dt < 4; ++dt) {
          int d = dt*32 + l31;
          half8 bv = *(const half8*)&VsL[d*KT + cp*8];
          Oacc[dt] = __builtin_amdgcn_mfma_f32_32x32x16_f16(fm.hv, bv, Oacc[dt], 0, 0, 0);
        }
        __builtin_amdgcn_s_setprio(0);
      }
    }
    __builtin_amdgcn_s_barrier();
    if (kt + 2 < NT) {
      STAGE_K(kt + 2, buf);
      STAGE_V(kt + 2, buf);
    }
  }
  float lpt = lp + __shfl_xor(lp, 32, 64);
  float rinv = 1.0f / lpt;
  float ri[16];
  #pragma unroll
  for (int r = 0; r < 16; ++r) {
    int row = (r & 3) + 8*(r >> 2) + 4*hi;
    ri[r] = __shfl(rinv, row, 64);
  }
  #pragma unroll
  for (int dt = 0; dt < 4; ++dt)
    #pragma unroll
    for (int r = 0; r < 16; ++r) {
      int row = (r & 3) + 8*(r >> 2) + 4*hi;
      int trow = qt*QTILE + w*32 + row;
      int col  = h*DK + dt*32 + l31;
      attn_out[((size_t)b*T_SEQ + trow)*1024 + col] = f2bf(Oacc[dt][r] * ri[r]);
    }
}

// ---------------------------------------------------------------------------
// Kernel 3: out = attn(8192,1024)bf16 @ Wu^T + bu (round-5 verbatim).
// ---------------------------------------------------------------------------
__global__ __launch_bounds__(256) void out_proj_kernel(
    const unsigned short* __restrict__ attnb, const unsigned short* __restrict__ Wub,
    const float* __restrict__ bu, float* __restrict__ out)
{
  int mb = blockIdx.x * 16;
  int t = threadIdx.x, wave = t >> 6, lane = t & 63;
  int n = lane & 15, q = lane >> 4;
  int nb2 = wave * 32;
  floatx4 acc[2];
  acc[0] = (floatx4){0.f,0.f,0.f,0.f};
  acc[1] = (floatx4){0.f,0.f,0.f,0.f};
  const unsigned short* ap = attnb + (size_t)(mb + n) * 1024;
  #pragma unroll 8
  for (int kc = 0; kc < 32; ++kc) {
    int ko = kc*32 + q*8;
    short8 a0 = *(const short8*)(ap + ko);
    #pragma unroll
    for (int cg = 0; cg < 2; ++cg) {
      short8 bw = *(const short8*)(Wub + (size_t)(nb2 + cg*16 + n) * 1024 + ko);
      acc[cg] = __builtin_amdgcn_mfma_f32_16x16x32_bf16(a0, bw, acc[cg], 0, 0, 0);
    }
  }
  #pragma unroll
  for (int cg = 0; cg < 2; ++cg)
    #pragma unroll
    for (int r = 0; r < 4; ++r) {
      int m = mb + q*4 + r;
      int c = nb2 + cg*16 + n;
      out[(size_t)m * 128 + c] = acc[cg][r] + bu[c];
    }
}

// ---------------------------------------------------------------------------
extern "C" void kernel_launch(void* const* d_in, const int* in_sizes, int n_in,
                              void* d_out, int out_size, void* d_ws, size_t ws_size,
                              hipStream_t stream) {
  const float* x  = (const float*)d_in[0];
  const float* Wq = (const float*)d_in[1];
  const float* Wk = (const float*)d_in[2];
  const float* Wv = (const float*)d_in[3];
  const float* Wu = (const float*)d_in[4];
  const float* bu = (const float*)d_in[5];
  float* out = (float*)d_out;

  const size_t NE  = (size_t)BATCH * NH * T_SEQ * DK;  // 8,388,608 elems
  const size_t WEL = (size_t)DK * DK * NH;             // 131,072 elems per W
  const size_t XEL = (size_t)BATCH * T_SEQ * DK;       // 1,048,576 elems (x)
  unsigned short* Qw   = (unsigned short*)d_ws;
  unsigned short* Kw   = Qw + NE;
  unsigned short* Vt   = Kw + NE;
  unsigned short* attn = Vt + NE;
  unsigned short* Wqb  = attn + NE;
  unsigned short* Wkb  = Wqb + WEL;
  unsigned short* Wvb  = Wkb + WEL;
  unsigned short* Wub  = Wvb + WEL;
  unsigned short* xb   = Wub + WEL;
  if (ws_size < (4 * NE + 4 * WEL + XEL) * sizeof(unsigned short)) return;

  convert_kernel<<<768, 256, 0, stream>>>(x, Wq, Wk, Wv, Wu,
                                          xb, Wqb, Wkb, Wvb, Wub);
  dim3 g1(8, 64, 3);
  qkv_proj_kernel<<<g1, 256, 0, stream>>>(xb, Wqb, Wkb, Wvb, Qw, Kw, Vt);
  attn_kernel<<<BATCH * NH * (T_SEQ / QTILE), 256, 0, stream>>>(Qw, Kw, Vt, attn);
  out_proj_kernel<<<BATCH * T_SEQ / 16, 256, 0, stream>>>(attn, Wub, bu, out);
}